// Round 11
// baseline (320.040 us; speedup 1.0000x reference)
//
#include <hip/hip_runtime.h>
#include <math.h>

// FlashDiffAttention on MI355X (gfx950). Round 14.
// Pipelined-phase fda: one barrier/phase, {PV(t) || QK(t+1)} merged so the
// serial QK->softmax->bar->PV chain disappears. K is read per-lane straight
// from kws (L2/L3-hot; same bytes the old sK staging copied) - sK deleted.
// sV 3-deep (prefetch t+2 issues at phase top, never collides with reads);
// sP double-buffered. Barrier = vmcnt(4)+lgkmcnt(0)+s_barrier:
//  - lgkmcnt(0): sP visible; all PV ds_reads retired before any wave's
//    next-phase V-prefetch overwrites that buffer.
//  - vmcnt(4): all but the newest 4 staging ops (= last phase's prefetch)
//    landed; kf data-dep waits transitively drain older prefetches.
//  - act-guard alignment: PV(t)-active waves issued kf(t) last phase.
// prep: UNCHANGED from round 13 (insensitive to rewrite; measure first).

#define S_LEN 2048
#define ROWSTR 2048
#define NEG_BIG (-3.0e38f)
#define QSCALE (1.44269504088896f * 0.0883883476483184f)
#define SM_SHIFT 20.0f
#define LAMBDA_INIT 0.783605766532f

typedef __attribute__((ext_vector_type(8))) short short8;
typedef __attribute__((ext_vector_type(4))) float f32x4;

__device__ __forceinline__ short f2bf(float f) {
    unsigned u = __builtin_bit_cast(unsigned, f);
    u += 0x7fffu + ((u >> 16) & 1u);
    return (short)(u >> 16);
}

__device__ __forceinline__ void async16(const short* g, short* l) {
    __builtin_amdgcn_global_load_lds(
        (const __attribute__((address_space(1))) unsigned int*)g,
        (__attribute__((address_space(3))) unsigned int*)l, 16, 0, 0);
}

// ---------------- prepass: one block per (bh, key-tile t) ----------------
__global__ __launch_bounds__(256)
void prep_kernel(const float* __restrict__ k, const float* __restrict__ v,
                 short* __restrict__ kws, short* __restrict__ vws) {
    __shared__ short sKL[8192];      // [attn][key][128] in FINAL swizzled layout
    __shared__ short sT[32][260];    // [key][n] transpose buffer
    const int tid = threadIdx.x;
    const int bh  = blockIdx.x >> 6;
    const int t   = blockIdx.x & 63;
    const int b   = bh >> 3;
    const int h   = bh & 7;

    // --- K loads: coalesced float4; convert; LDS at swizzled position ---
    {
        const int lh    = tid & 31;          // position within a 512B row
        const int c     = lh >> 1;           // 16B chunk 0..15
        const int half  = lh & 1;            // which 8B half of the chunk
        const int rbase = tid >> 5;          // 0..7
        #pragma unroll
        for (int p = 0; p < 8; ++p) {
            const int row  = p * 8 + rbase;  // 0..63
            const int attn = row >> 5;
            const int key  = row & 31;
            const float* src = k + (((size_t)(b * S_LEN + t * 32 + key) * 16) + 2 * h + attn) * 128 + lh * 4;
            const float4 a = *(const float4*)src;
            short4 sv;
            sv.x = f2bf(a.x); sv.y = f2bf(a.y); sv.z = f2bf(a.z); sv.w = f2bf(a.w);
            *(short4*)(sKL + attn * 4096 + key * 128 + ((c ^ (key & 7)) << 3) + half * 4) = sv;
        }
    }

    // --- V loads: coalesced float4 rows -> LDS [key][n] ---
    {
        const int n0 = (tid & 63) * 4;
        const int kb = tid >> 6;             // 0..3
        #pragma unroll
        for (int p = 0; p < 8; ++p) {
            const int key = p * 4 + kb;
            const float* src = v + (((size_t)(b * S_LEN + t * 32 + key) * 16) + 2 * h) * 128 + n0;
            const float4 a = *(const float4*)src;
            short4 sv;
            sv.x = f2bf(a.x); sv.y = f2bf(a.y); sv.z = f2bf(a.z); sv.w = f2bf(a.w);
            *(short4*)(&sT[key][n0]) = sv;
        }
    }
    __syncthreads();

    // --- K out: linear LDS read, fully coalesced store ---
    {
        short* kdst = kws + (((size_t)(bh * 64 + t)) << 13);
        #pragma unroll
        for (int i = 0; i < 4; ++i) {
            const short8 d = *(const short8*)(sKL + i * 2048 + tid * 8);
            *(short8*)(kdst + i * 2048 + tid * 8) = d;
        }
    }

    // --- V out: chunk-XOR-swizzled column gather, coalesced store ---
    {
        const int f = (tid >> 1) & 3;
        short vv[32];
        #pragma unroll
        for (int o = 0; o < 32; ++o)
            vv[o] = sT[(((o >> 3) ^ f) << 3) + (o & 7)][tid];
        short* vdst = vws + (((size_t)(bh * 64 + t)) << 13) + tid * 32;
        #pragma unroll
        for (int i = 0; i < 4; ++i)
            *(short8*)(vdst + i * 8) = *(short8*)&vv[i * 8];
    }
}

// ---------------- main kernel ----------------
__global__ __launch_bounds__(256)
void fda_kernel(const short* __restrict__ kws, const short* __restrict__ vws,
                const float* __restrict__ q,
                const float* __restrict__ lq1, const float* __restrict__ lk1,
                const float* __restrict__ lq2, const float* __restrict__ lk2,
                float* __restrict__ out) {
    __shared__ short sV[3][256][32];      // [vbuf][n][key chunk-swizzled]
    __shared__ short sP[2][2][64][40];    // [pbuf][attn][row][key] (+8 pad)
    __shared__ float sL[2][64];           // [attn][row] final l
    __shared__ float sRed[2][2][32];      // [rg][u][row] rms partials

    const int tid  = threadIdx.x;
    const int w    = tid >> 6;
    const int lane = tid & 63;
    const int mi   = lane & 15;
    const int quad = lane >> 4;
    const int rg   = w & 1;               // row half (32 rows)
    const int u    = w >> 1;              // attn (QK) / n-half (PV)

    const int bid = blockIdx.x;
    const int bh  = bid & 15;
    const int g   = bid >> 4;
    const int qt  = (g < 16) ? (31 - g) : (g - 16);  // balanced pairs
    const int b   = bh >> 3;
    const int h   = bh & 7;
    const int qbase = qt * 64;
    const int nt  = 2 * qt + 2;
    const int dlim = 2 * qt + rg;         // last active tile for this wave

    const short* ktile0 = kws + (((size_t)(bh * 64)) << 13);
    const short* vtile0 = vws + (((size_t)(bh * 64)) << 13);

    // ---- lambda_full ----
    float d1 = lq1[lane] * lk1[lane] + lq1[lane + 64] * lk1[lane + 64];
    float d2 = lq2[lane] * lk2[lane] + lq2[lane + 64] * lk2[lane + 64];
    #pragma unroll
    for (int off = 32; off; off >>= 1) {
        d1 += __shfl_xor(d1, off);
        d2 += __shfl_xor(d2, off);
    }
    const float lambda_full = expf(d1) - expf(d2) + LAMBDA_INIT;

    // ---- stage V tiles 0,1 (8 async16 per wave) ----
    #pragma unroll
    for (int i = 0; i < 4; ++i) {
        const int ch = (w * 4 + i) * 512;
        async16(vtile0 + ch + lane * 8, &sV[0][0][0] + ch);
    }
    #pragma unroll
    for (int i = 0; i < 4; ++i) {
        const int ch = (w * 4 + i) * 512;
        async16(vtile0 + 8192 + ch + lane * 8, &sV[1][0][0] + ch);
    }

    // ---- Q fragments (attn = u): direct fp32 load, scale+convert ----
    short8 qf[2][4];
    #pragma unroll
    for (int m = 0; m < 2; ++m) {
        const int row = qbase + rg * 32 + m * 16 + mi;
        const float* qr = q + (((size_t)(b * S_LEN + row) * 16) + 2 * h + u) * 128 + quad * 8;
        #pragma unroll
        for (int db = 0; db < 4; ++db) {
            float4 a0 = *(const float4*)(qr + db * 32);
            float4 a1 = *(const float4*)(qr + db * 32 + 4);
            short8 sv;
            sv[0]=f2bf(a0.x*QSCALE); sv[1]=f2bf(a0.y*QSCALE); sv[2]=f2bf(a0.z*QSCALE); sv[3]=f2bf(a0.w*QSCALE);
            sv[4]=f2bf(a1.x*QSCALE); sv[5]=f2bf(a1.y*QSCALE); sv[6]=f2bf(a1.z*QSCALE); sv[7]=f2bf(a1.w*QSCALE);
            qf[m][db] = sv;
        }
    }

    // ---- per-lane kf byte... short offsets within a tile ----
    int koff[2][4];
    #pragma unroll
    for (int kh = 0; kh < 2; ++kh)
        #pragma unroll
        for (int db = 0; db < 4; ++db)
            koff[kh][db] = u * 4096 + kh * 2048 + mi * 128 +
                           ((((db << 2) + quad) ^ (mi & 7)) << 3);

    // ---- state ----
    float l[2][4] = {{0.f,0.f,0.f,0.f},{0.f,0.f,0.f,0.f}};
    f32x4 O[2][2][8];                      // [attn][m][nb]
    #pragma unroll
    for (int a = 0; a < 2; ++a)
        #pragma unroll
        for (int m = 0; m < 2; ++m)
            #pragma unroll
            for (int nb = 0; nb < 8; ++nb)
                O[a][m][nb] = (f32x4){0.f, 0.f, 0.f, 0.f};

    const int vswz = (quad ^ ((mi >> 1) & 3)) << 3;   // sV chunk swizzle decode

    // ---- prologue: QK(0) -> sP[0] (kf direct from global; mask if diag) ----
    {
        short8 kf[2][4];
        #pragma unroll
        for (int kh = 0; kh < 2; ++kh)
            #pragma unroll
            for (int db = 0; db < 4; ++db)
                kf[kh][db] = *(const short8*)(ktile0 + koff[kh][db]);
        f32x4 S[2][2];
        #pragma unroll
        for (int m = 0; m < 2; ++m)
            #pragma unroll
            for (int kh = 0; kh < 2; ++kh)
                S[m][kh] = (f32x4){0.f, 0.f, 0.f, 0.f};
        __builtin_amdgcn_s_setprio(1);
        #pragma unroll
        for (int db = 0; db < 4; ++db)
            #pragma unroll
            for (int kh = 0; kh < 2; ++kh) {
                S[0][kh] = __builtin_amdgcn_mfma_f32_16x16x32_bf16(qf[0][db], kf[kh][db], S[0][kh], 0, 0, 0);
                S[1][kh] = __builtin_amdgcn_mfma_f32_16x16x32_bf16(qf[1][db], kf[kh][db], S[1][kh], 0, 0, 0);
            }
        __builtin_amdgcn_s_setprio(0);
        if (0 == dlim) {                   // qt==0, rg==0: tile 0 is diagonal
            #pragma unroll
            for (int m = 0; m < 2; ++m)
                #pragma unroll
                for (int kh = 0; kh < 2; ++kh)
                    #pragma unroll
                    for (int r = 0; r < 4; ++r)
                        if (kh * 16 + mi > qbase + m * 16 + quad * 4 + r)
                            S[m][kh][r] = NEG_BIG;
        }
        #pragma unroll
        for (int m = 0; m < 2; ++m) {
            short* pp = &sP[0][u][rg * 32 + m * 16 + quad * 4][mi];
            #pragma unroll
            for (int r = 0; r < 4; ++r) {
                const float pa = exp2f(S[m][0][r] - SM_SHIFT);
                const float pb = exp2f(S[m][1][r] - SM_SHIFT);
                l[m][r] += pa + pb;
                pp[r * 40]      = f2bf(pa);
                pp[r * 40 + 16] = f2bf(pb);
            }
        }
    }

    // ---- pipelined main loop: one barrier per phase ----
    for (int t = 0; t < nt; ++t) {
        asm volatile("s_waitcnt vmcnt(4) lgkmcnt(0)\n\ts_barrier" ::: "memory");
        const int cur  = t % 3;
        const int pcur = t & 1;
        const int pnxt = (t + 1) & 1;
        const bool act_pv = (t <= dlim);
        const bool act_qk = (t + 1 <= dlim);

        // kf loads for QK(t+1) FIRST (their data-dep wait transitively
        // drains prefetches older than this phase's)
        short8 kf[2][4];
        if (act_qk) {
            const short* kt = ktile0 + (((size_t)(t + 1)) << 13);
            #pragma unroll
            for (int kh = 0; kh < 2; ++kh)
                #pragma unroll
                for (int db = 0; db < 4; ++db)
                    kf[kh][db] = *(const short8*)(kt + koff[kh][db]);
        }

        // V prefetch for tile t+2 into sV[(t+2)%3] (never collides with
        // cur or next reads; lands by top of phase t+2)
        if (t + 2 < nt) {
            const short* vt = vtile0 + (((size_t)(t + 2)) << 13);
            short* dv = &sV[(t + 2) % 3][0][0];
            #pragma unroll
            for (int i = 0; i < 4; ++i) {
                const int ch = (w * 4 + i) * 512;
                async16(vt + ch + lane * 8, dv + ch);
            }
        }

        // ---- PV(t): sP[pcur] x sV[cur] -> O ----
        if (act_pv) {
            short8 pA[2][2];
            #pragma unroll
            for (int a = 0; a < 2; ++a)
                #pragma unroll
                for (int m = 0; m < 2; ++m)
                    pA[a][m] = *(const short8*)&sP[pcur][a][rg * 32 + m * 16 + mi][quad * 8];
            __builtin_amdgcn_s_setprio(1);
            #pragma unroll
            for (int nb = 0; nb < 8; ++nb) {
                const short8 bv = *(const short8*)&sV[cur][u * 128 + nb * 16 + mi][vswz];
                O[0][0][nb] = __builtin_amdgcn_mfma_f32_16x16x32_bf16(pA[0][0], bv, O[0][0][nb], 0, 0, 0);
                O[0][1][nb] = __builtin_amdgcn_mfma_f32_16x16x32_bf16(pA[0][1], bv, O[0][1][nb], 0, 0, 0);
                O[1][0][nb] = __builtin_amdgcn_mfma_f32_16x16x32_bf16(pA[1][0], bv, O[1][0][nb], 0, 0, 0);
                O[1][1][nb] = __builtin_amdgcn_mfma_f32_16x16x32_bf16(pA[1][1], bv, O[1][1][nb], 0, 0, 0);
            }
            __builtin_amdgcn_s_setprio(0);
        }

        // ---- QK(t+1) + softmax -> sP[pnxt] ----
        if (act_qk) {
            f32x4 S[2][2];
            #pragma unroll
            for (int m = 0; m < 2; ++m)
                #pragma unroll
                for (int kh = 0; kh < 2; ++kh)
                    S[m][kh] = (f32x4){0.f, 0.f, 0.f, 0.f};
            __builtin_amdgcn_s_setprio(1);
            #pragma unroll
            for (int db = 0; db < 4; ++db)
                #pragma unroll
                for (int kh = 0; kh < 2; ++kh) {
                    S[0][kh] = __builtin_amdgcn_mfma_f32_16x16x32_bf16(qf[0][db], kf[kh][db], S[0][kh], 0, 0, 0);
                    S[1][kh] = __builtin_amdgcn_mfma_f32_16x16x32_bf16(qf[1][db], kf[kh][db], S[1][kh], 0, 0, 0);
                }
            __builtin_amdgcn_s_setprio(0);
            if (t + 1 == dlim) {          // diagonal tile for this wave
                const int qr0 = qbase + rg * 32;
                #pragma unroll
                for (int m = 0; m < 2; ++m)
                    #pragma unroll
                    for (int kh = 0; kh < 2; ++kh)
                        #pragma unroll
                        for (int r = 0; r < 4; ++r)
                            if ((t + 1) * 32 + kh * 16 + mi > qr0 + m * 16 + quad * 4 + r)
                                S[m][kh][r] = NEG_BIG;
            }
            #pragma unroll
            for (int m = 0; m < 2; ++m) {
                short* pp = &sP[pnxt][u][rg * 32 + m * 16 + quad * 4][mi];
                #pragma unroll
                for (int r = 0; r < 4; ++r) {
                    const float pa = exp2f(S[m][0][r] - SM_SHIFT);
                    const float pb = exp2f(S[m][1][r] - SM_SHIFT);
                    l[m][r] += pa + pb;
                    pp[r * 40]      = f2bf(pa);
                    pp[r * 40 + 16] = f2bf(pb);
                }
            }
        }
    }

    // ---- epilogue ----
    #pragma unroll
    for (int m = 0; m < 2; ++m)
        #pragma unroll
        for (int r = 0; r < 4; ++r) {
            float s = l[m][r];
            s += __shfl_xor(s, 1); s += __shfl_xor(s, 2);
            s += __shfl_xor(s, 4); s += __shfl_xor(s, 8);
            l[m][r] = s;
        }
    if (mi == 0) {
        #pragma unroll
        for (int m = 0; m < 2; ++m)
            #pragma unroll
            for (int r = 0; r < 4; ++r)
                sL[u][rg * 32 + m * 16 + quad * 4 + r] = l[m][r];
    }
    __syncthreads();

    float ss[2][4] = {{0.f,0.f,0.f,0.f},{0.f,0.f,0.f,0.f}};
    #pragma unroll
    for (int m = 0; m < 2; ++m)
        #pragma unroll
        for (int r = 0; r < 4; ++r) {
            const int row = rg * 32 + m * 16 + quad * 4 + r;
            const float il1 = 1.0f / sL[0][row];
            const float il2 = lambda_full / sL[1][row];
            #pragma unroll
            for (int nb = 0; nb < 8; ++nb) {
                const float c = O[0][m][nb][r] * il1 - O[1][m][nb][r] * il2;
                O[0][m][nb][r] = c;
                ss[m][r] += c * c;
            }
        }
    #pragma unroll
    for (int m = 0; m < 2; ++m)
        #pragma unroll
        for (int r = 0; r < 4; ++r) {
            float s = ss[m][r];
            s += __shfl_xor(s, 1); s += __shfl_xor(s, 2);
            s += __shfl_xor(s, 4); s += __shfl_xor(s, 8);
            ss[m][r] = s;
        }
    if (mi == 0) {
        #pragma unroll
        for (int m = 0; m < 2; ++m)
            #pragma unroll
            for (int r = 0; r < 4; ++r)
                sRed[rg][u][m * 16 + quad * 4 + r] = ss[m][r];
    }
    __syncthreads();

    #pragma unroll
    for (int m = 0; m < 2; ++m)
        #pragma unroll
        for (int r = 0; r < 4; ++r) {
            const int rl  = m * 16 + quad * 4 + r;
            const float tot = ss[m][r] + sRed[rg][u ^ 1][rl];
            const float scale = rsqrtf(tot * (1.0f / 256.0f) + 1e-5f) * (1.0f - LAMBDA_INIT);
            const int gr = qbase + rg * 32 + rl;
            float* ob = out + ((size_t)(b * S_LEN + gr)) * ROWSTR + h * 256 + u * 128 + mi;
            #pragma unroll
            for (int nb = 0; nb < 8; ++nb)
                ob[nb * 16] = O[0][m][nb][r] * scale;
        }
}

extern "C" void kernel_launch(void* const* d_in, const int* in_sizes, int n_in,
                              void* d_out, int out_size, void* d_ws, size_t ws_size,
                              hipStream_t stream) {
    (void)in_sizes; (void)n_in; (void)out_size; (void)ws_size;
    const float* q   = (const float*)d_in[0];
    const float* k   = (const float*)d_in[1];
    const float* v   = (const float*)d_in[2];
    const float* lq1 = (const float*)d_in[3];
    const float* lk1 = (const float*)d_in[4];
    const float* lq2 = (const float*)d_in[5];
    const float* lk2 = (const float*)d_in[6];
    float* out = (float*)d_out;

    short* kws = (short*)d_ws;                 // 16 bh x 64 tiles x 8192 shorts
    short* vws = kws + (size_t)16 * 64 * 8192; // total 33.6 MB

    prep_kernel<<<dim3(1024), dim3(256), 0, stream>>>(k, v, kws, vws);
    fda_kernel<<<dim3(512), dim3(256), 0, stream>>>(kws, vws, q,
                                                    lq1, lk1, lq2, lk2, out);
}

// Round 13
// 246.556 us; speedup vs baseline: 1.2980x; 1.2980x over previous
//
#include <hip/hip_runtime.h>
#include <math.h>

// FlashDiffAttention on MI355X (gfx950). Round 16.
// Base = round 12 (best verified: fda 128.4us / total 245.9us). Swapped-QK
// abandoned: needs ~304 regs -> 1 wave/SIMD free (183us) or miscompiles
// capped (2/2 failures). r12 is LDS-issue-bound (20 b128 reads + 16 scalar
// u16 writes per wave/tile ~= phase time). Changes:
//  (1) fda: interleaved-pair P layout - lane packs (pa,pb) = keys (mi,mi+16)
//      into ONE u32 -> 8 ds_write_b32 (was 16 ds_write_u16). sP2 u32
//      [2][64][20] (pad: writes 2-way/free, b128 reads aligned+conflict-free).
//      PV A-frag keys become interleaved key(e)=quad*4+(e>>1)+(e&1)*16;
//      prep stores V with the matching sigma permutation (verified both sides).
//  (2) prep: batch all 16 global loads into regs before convert+LDS writes
//      (latency exposure probe; 3rd strike -> prep closed).

#define S_LEN 2048
#define ROWSTR 2048
#define NEG_BIG (-3.0e38f)
#define QSCALE (1.44269504088896f * 0.0883883476483184f)
#define SM_SHIFT 20.0f
#define LAMBDA_INIT 0.783605766532f

typedef __attribute__((ext_vector_type(8))) short short8;
typedef __attribute__((ext_vector_type(4))) float f32x4;

__device__ __forceinline__ short f2bf(float f) {
    unsigned u = __builtin_bit_cast(unsigned, f);
    u += 0x7fffu + ((u >> 16) & 1u);
    return (short)(u >> 16);
}

__device__ __forceinline__ unsigned pack2bf(float a, float b) {
    return (unsigned)(unsigned short)f2bf(a) | ((unsigned)(unsigned short)f2bf(b) << 16);
}

__device__ __forceinline__ void async16(const short* g, short* l) {
    __builtin_amdgcn_global_load_lds(
        (const __attribute__((address_space(1))) unsigned int*)g,
        (__attribute__((address_space(3))) unsigned int*)l, 16, 0, 0);
}

// ---------------- prepass: one block per (bh, key-tile t) ----------------
__global__ __launch_bounds__(256)
void prep_kernel(const float* __restrict__ k, const float* __restrict__ v,
                 short* __restrict__ kws, short* __restrict__ vws) {
    __shared__ short sKL[8192];      // [attn][key][128] in FINAL swizzled layout
    __shared__ short sT[32][260];    // [key][n] transpose buffer
    const int tid = threadIdx.x;
    const int bh  = blockIdx.x >> 6;
    const int t   = blockIdx.x & 63;
    const int b   = bh >> 3;
    const int h   = bh & 7;

    // --- issue ALL 16 global loads first (max outstanding), then convert ---
    float4 ka[8], va[8];
    {
        const int lh    = tid & 31;
        const int rbase = tid >> 5;
        #pragma unroll
        for (int p = 0; p < 8; ++p) {
            const int row  = p * 8 + rbase;
            const int attn = row >> 5;
            const int key  = row & 31;
            ka[p] = *(const float4*)(k + (((size_t)(b * S_LEN + t * 32 + key) * 16) + 2 * h + attn) * 128 + lh * 4);
        }
        const int n0 = (tid & 63) * 4;
        const int kb = tid >> 6;
        #pragma unroll
        for (int p = 0; p < 8; ++p) {
            const int key = p * 4 + kb;
            va[p] = *(const float4*)(v + (((size_t)(b * S_LEN + t * 32 + key) * 16) + 2 * h) * 128 + n0);
        }
    }
    // --- K: convert + LDS at swizzled position ---
    {
        const int lh    = tid & 31;
        const int c     = lh >> 1;
        const int half  = lh & 1;
        const int rbase = tid >> 5;
        #pragma unroll
        for (int p = 0; p < 8; ++p) {
            const int row  = p * 8 + rbase;
            const int attn = row >> 5;
            const int key  = row & 31;
            short4 sv;
            sv.x = f2bf(ka[p].x); sv.y = f2bf(ka[p].y); sv.z = f2bf(ka[p].z); sv.w = f2bf(ka[p].w);
            *(short4*)(sKL + attn * 4096 + key * 128 + ((c ^ (key & 7)) << 3) + half * 4) = sv;
        }
    }
    // --- V: convert + LDS [key][n] ---
    {
        const int n0 = (tid & 63) * 4;
        const int kb = tid >> 6;
        #pragma unroll
        for (int p = 0; p < 8; ++p) {
            const int key = p * 4 + kb;
            short4 sv;
            sv.x = f2bf(va[p].x); sv.y = f2bf(va[p].y); sv.z = f2bf(va[p].z); sv.w = f2bf(va[p].w);
            *(short4*)(&sT[key][n0]) = sv;
        }
    }
    __syncthreads();

    // --- K out: linear LDS read, fully coalesced store ---
    {
        short* kdst = kws + (((size_t)(bh * 64 + t)) << 13);
        #pragma unroll
        for (int i = 0; i < 4; ++i) {
            const short8 d = *(const short8*)(sKL + i * 2048 + tid * 8);
            *(short8*)(kdst + i * 2048 + tid * 8) = d;
        }
    }

    // --- V out: sigma-permuted column gather (interleaved keys + chunk-XOR),
    //     coalesced store. Physical chunk p, slot s (0..7):
    //     orig key = (p^f)*4 + (s>>1) + (s&1)*16
    {
        const int f = (tid >> 1) & 3;
        short vv[32];
        #pragma unroll
        for (int p = 0; p < 4; ++p)
            #pragma unroll
            for (int s = 0; s < 8; ++s)
                vv[p * 8 + s] = sT[((p ^ f) << 2) + (s >> 1) + ((s & 1) << 4)][tid];
        short* vdst = vws + (((size_t)(bh * 64 + t)) << 13) + tid * 32;
        #pragma unroll
        for (int i = 0; i < 4; ++i)
            *(short8*)(vdst + i * 8) = *(short8*)&vv[i * 8];
    }
}

// ---------------- main kernel ----------------
__global__ __launch_bounds__(256, 2)
void fda_kernel(const short* __restrict__ kws, const short* __restrict__ vws,
                const float* __restrict__ q,
                const float* __restrict__ lq1, const float* __restrict__ lk1,
                const float* __restrict__ lq2, const float* __restrict__ lk2,
                float* __restrict__ out) {
    __shared__ short sK[2][2][32][128];   // [buf][attn][key][d swizzled]
    __shared__ short sV[2][256][32];      // [buf][n][key sigma-permuted]
    __shared__ unsigned sP2[2][64][20];   // [attn][row][packed key-pair] (+4 pad)
    __shared__ float sL[2][64];           // [attn][row] final l
    __shared__ float sRed[2][2][32];      // [rg][u][row] rms partials

    const int tid  = threadIdx.x;
    const int w    = tid >> 6;
    const int lane = tid & 63;
    const int mi   = lane & 15;
    const int quad = lane >> 4;
    const int rg   = w & 1;               // row half (32 rows)
    const int u    = w >> 1;              // attn (QK) / n-half (PV)

    const int bid = blockIdx.x;
    const int bh  = bid & 15;
    const int g   = bid >> 4;
    const int qt  = (g < 16) ? (31 - g) : (g - 16);  // balanced pairs
    const int b   = bh >> 3;
    const int h   = bh & 7;
    const int qbase = qt * 64;
    const int nt  = 2 * qt + 2;

    const short* ktile0 = kws + (((size_t)(bh * 64)) << 13);
    const short* vtile0 = vws + (((size_t)(bh * 64)) << 13);

    // ---- stage tile 0 (issue first; overlaps Q load + lambda) ----
    {
        short* dk = &sK[0][0][0][0];
        short* dv = &sV[0][0][0];
        #pragma unroll
        for (int i = 0; i < 4; ++i) {
            const int ch = (w * 4 + i) * 512;
            async16(ktile0 + ch + lane * 8, dk + ch);
            async16(vtile0 + ch + lane * 8, dv + ch);
        }
    }

    // ---- lambda_full ----
    float d1 = lq1[lane] * lk1[lane] + lq1[lane + 64] * lk1[lane + 64];
    float d2 = lq2[lane] * lk2[lane] + lq2[lane + 64] * lk2[lane + 64];
    #pragma unroll
    for (int off = 32; off; off >>= 1) {
        d1 += __shfl_xor(d1, off);
        d2 += __shfl_xor(d2, off);
    }
    const float lambda_full = expf(d1) - expf(d2) + LAMBDA_INIT;

    // ---- Q fragments (attn = u): direct fp32 load, scale+convert ----
    short8 qf[2][4];
    #pragma unroll
    for (int m = 0; m < 2; ++m) {
        const int row = qbase + rg * 32 + m * 16 + mi;
        const float* qr = q + (((size_t)(b * S_LEN + row) * 16) + 2 * h + u) * 128 + quad * 8;
        #pragma unroll
        for (int db = 0; db < 4; ++db) {
            float4 a0 = *(const float4*)(qr + db * 32);
            float4 a1 = *(const float4*)(qr + db * 32 + 4);
            short8 sv;
            sv[0]=f2bf(a0.x*QSCALE); sv[1]=f2bf(a0.y*QSCALE); sv[2]=f2bf(a0.z*QSCALE); sv[3]=f2bf(a0.w*QSCALE);
            sv[4]=f2bf(a1.x*QSCALE); sv[5]=f2bf(a1.y*QSCALE); sv[6]=f2bf(a1.z*QSCALE); sv[7]=f2bf(a1.w*QSCALE);
            qf[m][db] = sv;
        }
    }

    // ---- state ----
    float l[2][4] = {{0.f,0.f,0.f,0.f},{0.f,0.f,0.f,0.f}};
    f32x4 O[2][2][8];                      // [attn][m][nb]
    #pragma unroll
    for (int a = 0; a < 2; ++a)
        #pragma unroll
        for (int m = 0; m < 2; ++m)
            #pragma unroll
            for (int nb = 0; nb < 8; ++nb)
                O[a][m][nb] = (f32x4){0.f, 0.f, 0.f, 0.f};

    const int vswz = (quad ^ ((mi >> 1) & 3)) << 3;   // sV chunk swizzle decode

    for (int t = 0; t < nt; ++t) {
        __syncthreads();                  // B1: buf[t&1] staged, buf^1 consumed
        const int buf = t & 1;

        // prefetch next tile (full QK+softmax+PV window to land)
        if (t + 1 < nt) {
            const short* kt = ktile0 + (((size_t)(t + 1)) << 13);
            const short* vt = vtile0 + (((size_t)(t + 1)) << 13);
            short* dk = &sK[buf ^ 1][0][0][0];
            short* dv = &sV[buf ^ 1][0][0];
            #pragma unroll
            for (int i = 0; i < 4; ++i) {
                const int ch = (w * 4 + i) * 512;
                async16(kt + ch + lane * 8, dk + ch);
                async16(vt + ch + lane * 8, dv + ch);
            }
        }

        const bool act = (t <= 2 * qt + rg);
        if (act) {
            f32x4 S[2][2];
            #pragma unroll
            for (int m = 0; m < 2; ++m)
                #pragma unroll
                for (int kh = 0; kh < 2; ++kh)
                    S[m][kh] = (f32x4){0.f, 0.f, 0.f, 0.f};
            const short* kb = &sK[buf][u][0][0];
            __builtin_amdgcn_s_setprio(1);
            #pragma unroll
            for (int db = 0; db < 4; ++db) {
                #pragma unroll
                for (int kh = 0; kh < 2; ++kh) {
                    const short8 kf = *(const short8*)(kb + (kh * 16 + mi) * 128 +
                                       ((((db << 2) + quad) ^ (mi & 7)) << 3));
                    S[0][kh] = __builtin_amdgcn_mfma_f32_16x16x32_bf16(qf[0][db], kf, S[0][kh], 0, 0, 0);
                    S[1][kh] = __builtin_amdgcn_mfma_f32_16x16x32_bf16(qf[1][db], kf, S[1][kh], 0, 0, 0);
                }
            }
            __builtin_amdgcn_s_setprio(0);
            if (t == 2 * qt + rg) {       // diagonal tile: causal mask
                const int qr0 = qbase + rg * 32;
                #pragma unroll
                for (int m = 0; m < 2; ++m)
                    #pragma unroll
                    for (int kh = 0; kh < 2; ++kh)
                        #pragma unroll
                        for (int r = 0; r < 4; ++r)
                            if (t * 32 + kh * 16 + mi > qr0 + m * 16 + quad * 4 + r)
                                S[m][kh][r] = NEG_BIG;
            }
            // static-shift softmax; pack (key mi, key mi+16) into one u32
            #pragma unroll
            for (int m = 0; m < 2; ++m) {
                unsigned* pp = &sP2[u][rg * 32 + m * 16 + quad * 4][mi];
                #pragma unroll
                for (int r = 0; r < 4; ++r) {
                    const float pa = exp2f(S[m][0][r] - SM_SHIFT);
                    const float pb = exp2f(S[m][1][r] - SM_SHIFT);
                    l[m][r] += pa + pb;
                    pp[r * 20] = pack2bf(pa, pb);
                }
            }
        }
        __syncthreads();                  // B3: sP2 visible

        if (act) {
            short8 pA[2][2];
            #pragma unroll
            for (int a = 0; a < 2; ++a)
                #pragma unroll
                for (int m = 0; m < 2; ++m)
                    pA[a][m] = *(const short8*)&sP2[a][rg * 32 + m * 16 + mi][quad * 4];
            __builtin_amdgcn_s_setprio(1);
            #pragma unroll
            for (int nb = 0; nb < 8; ++nb) {
                const short8 bv = *(const short8*)&sV[buf][u * 128 + nb * 16 + mi][vswz];
                O[0][0][nb] = __builtin_amdgcn_mfma_f32_16x16x32_bf16(pA[0][0], bv, O[0][0][nb], 0, 0, 0);
                O[0][1][nb] = __builtin_amdgcn_mfma_f32_16x16x32_bf16(pA[0][1], bv, O[0][1][nb], 0, 0, 0);
                O[1][0][nb] = __builtin_amdgcn_mfma_f32_16x16x32_bf16(pA[1][0], bv, O[1][0][nb], 0, 0, 0);
                O[1][1][nb] = __builtin_amdgcn_mfma_f32_16x16x32_bf16(pA[1][1], bv, O[1][1][nb], 0, 0, 0);
            }
            __builtin_amdgcn_s_setprio(0);
        }
    }

    // ---- epilogue ----
    #pragma unroll
    for (int m = 0; m < 2; ++m)
        #pragma unroll
        for (int r = 0; r < 4; ++r) {
            float s = l[m][r];
            s += __shfl_xor(s, 1); s += __shfl_xor(s, 2);
            s += __shfl_xor(s, 4); s += __shfl_xor(s, 8);
            l[m][r] = s;
        }
    if (mi == 0) {
        #pragma unroll
        for (int m = 0; m < 2; ++m)
            #pragma unroll
            for (int r = 0; r < 4; ++r)
                sL[u][rg * 32 + m * 16 + quad * 4 + r] = l[m][r];
    }
    __syncthreads();

    float ss[2][4] = {{0.f,0.f,0.f,0.f},{0.f,0.f,0.f,0.f}};
    #pragma unroll
    for (int m = 0; m < 2; ++m)
        #pragma unroll
        for (int r = 0; r < 4; ++r) {
            const int row = rg * 32 + m * 16 + quad * 4 + r;
            const float il1 = 1.0f / sL[0][row];
            const float il2 = lambda_full / sL[1][row];
            #pragma unroll
            for (int nb = 0; nb < 8; ++nb) {
                const float c = O[0][m][nb][r] * il1 - O[1][m][nb][r] * il2;
                O[0][m][nb][r] = c;
                ss[m][r] += c * c;
            }
        }
    #pragma unroll
    for (int m = 0; m < 2; ++m)
        #pragma unroll
        for (int r = 0; r < 4; ++r) {
            float s = ss[m][r];
            s += __shfl_xor(s, 1); s += __shfl_xor(s, 2);
            s += __shfl_xor(s, 4); s += __shfl_xor(s, 8);
            ss[m][r] = s;
        }
    if (mi == 0) {
        #pragma unroll
        for (int m = 0; m < 2; ++m)
            #pragma unroll
            for (int r = 0; r < 4; ++r)
                sRed[rg][u][m * 16 + quad * 4 + r] = ss[m][r];
    }
    __syncthreads();

    #pragma unroll
    for (int m = 0; m < 2; ++m)
        #pragma unroll
        for (int r = 0; r < 4; ++r) {
            const int rl  = m * 16 + quad * 4 + r;
            const float tot = ss[m][r] + sRed[rg][u ^ 1][rl];
            const float scale = rsqrtf(tot * (1.0f / 256.0f) + 1e-5f) * (1.0f - LAMBDA_INIT);
            const int gr = qbase + rg * 32 + rl;
            float* ob = out + ((size_t)(b * S_LEN + gr)) * ROWSTR + h * 256 + u * 128 + mi;
            #pragma unroll
            for (int nb = 0; nb < 8; ++nb)
                ob[nb * 16] = O[0][m][nb][r] * scale;
        }
}

extern "C" void kernel_launch(void* const* d_in, const int* in_sizes, int n_in,
                              void* d_out, int out_size, void* d_ws, size_t ws_size,
                              hipStream_t stream) {
    (void)in_sizes; (void)n_in; (void)out_size; (void)ws_size;
    const float* q   = (const float*)d_in[0];
    const float* k   = (const float*)d_in[1];
    const float* v   = (const float*)d_in[2];
    const float* lq1 = (const float*)d_in[3];
    const float* lk1 = (const float*)d_in[4];
    const float* lq2 = (const float*)d_in[5];
    const float* lk2 = (const float*)d_in[6];
    float* out = (float*)d_out;

    short* kws = (short*)d_ws;                 // 16 bh x 64 tiles x 8192 shorts
    short* vws = kws + (size_t)16 * 64 * 8192; // total 33.6 MB

    prep_kernel<<<dim3(1024), dim3(256), 0, stream>>>(k, v, kws, vws);
    fda_kernel<<<dim3(512), dim3(256), 0, stream>>>(kws, vws, q,
                                                    lq1, lk1, lq2, lk2, out);
}